// Round 5
// baseline (846.726 us; speedup 1.0000x reference)
//
#include <hip/hip_runtime.h>

#define SCAN_T 1024

// ---------------- CSR build ----------------

__global__ void k_hist(const int* __restrict__ row, int* __restrict__ cnt, int nnz) {
    int i = blockIdx.x * blockDim.x + threadIdx.x;
    if (i < nnz) atomicAdd(&cnt[row[i]], 1);
}

__global__ void k_blocksum(const int* __restrict__ cnt, int* __restrict__ bsum, int n) {
    __shared__ int sm[SCAN_T];
    int tid = threadIdx.x;
    int i = blockIdx.x * SCAN_T + tid;
    int x = (i < n) ? cnt[i] : 0;
    sm[tid] = x;
    __syncthreads();
    for (int off = SCAN_T / 2; off > 0; off >>= 1) {
        if (tid < off) sm[tid] += sm[tid + off];
        __syncthreads();
    }
    if (tid == 0) bsum[blockIdx.x] = sm[0];
}

// single block: in-place exclusive scan of bsum[nchunk]
__global__ void k_scan_bsum(int* __restrict__ bsum, int nchunk) {
    __shared__ int sm[SCAN_T];
    int tid = threadIdx.x;
    int running = 0;
    for (int base = 0; base < nchunk; base += SCAN_T) {
        int i = base + tid;
        int x = (i < nchunk) ? bsum[i] : 0;
        sm[tid] = x;
        __syncthreads();
        for (int off = 1; off < SCAN_T; off <<= 1) {
            int v = (tid >= off) ? sm[tid - off] : 0;
            __syncthreads();
            sm[tid] += v;
            __syncthreads();
        }
        int incl = sm[tid];
        int total = sm[SCAN_T - 1];
        if (i < nchunk) bsum[i] = running + incl - x;  // exclusive
        running += total;
        __syncthreads();
    }
}

__global__ void k_write_ptr(const int* __restrict__ cnt, const int* __restrict__ boff,
                            int* __restrict__ rp, int n) {
    __shared__ int sm[SCAN_T];
    int tid = threadIdx.x;
    int i = blockIdx.x * SCAN_T + tid;
    int x = (i < n) ? cnt[i] : 0;
    sm[tid] = x;
    __syncthreads();
    for (int off = 1; off < SCAN_T; off <<= 1) {
        int v = (tid >= off) ? sm[tid - off] : 0;
        __syncthreads();
        sm[tid] += v;
        __syncthreads();
    }
    int incl = sm[tid];
    int base = boff[blockIdx.x];
    if (i < n) rp[i] = base + incl - x;       // exclusive
    if (i == n - 1) rp[n] = base + incl;      // total
}

__global__ void k_scatter(const int* __restrict__ row, const int* __restrict__ col,
                          const float* __restrict__ val, int* __restrict__ fill,
                          int2* __restrict__ scv, int nnz) {
    int i = blockIdx.x * blockDim.x + threadIdx.x;
    if (i >= nnz) return;
    int r = row[i];
    int p = atomicAdd(&fill[r], 1);
    int2 v;
    v.x = col[i];
    v.y = __float_as_int(0.9f * val[i]);   // fold (1-alpha) here
    scv[p] = v;
}

// ---- SpMM: persistent waves, grid-stride over rows. Per row: 16 edges/trip
// (4 gathers in flight), 16 lanes/edge-group, float4/lane. Tail: index clamped
// (same-address dup loads coalesce) + value predication.

__device__ __forceinline__ float4 shfl_xor4(float4 v, int m) {
    float4 r;
    r.x = __shfl_xor(v.x, m, 64);
    r.y = __shfl_xor(v.y, m, 64);
    r.z = __shfl_xor(v.z, m, 64);
    r.w = __shfl_xor(v.w, m, 64);
    return r;
}

__global__ __launch_bounds__(256) void k_spmm16p(const float4* __restrict__ src,
                                                 float4* __restrict__ dst,
                                                 const float4* __restrict__ E,
                                                 const int* __restrict__ rp,
                                                 const int2* __restrict__ scv, int n) {
    int lane = threadIdx.x & 63;
    int g = lane >> 4;   // edge group 0..3
    int q = lane & 15;   // feature quarter (4 floats each)
    int wid0 = (blockIdx.x * blockDim.x + threadIdx.x) >> 6;
    int nwav = (gridDim.x * blockDim.x) >> 6;
    for (int wid = wid0; wid < n; wid += nwav) {
        int s = rp[wid];
        int e = rp[wid + 1];
        float4 acc = make_float4(0.f, 0.f, 0.f, 0.f);
        for (int j = s; j < e; j += 16) {
            int j0 = j + g, j1 = j + 4 + g, j2 = j + 8 + g, j3 = j + 12 + g;
            int i0 = min(j0, e - 1);
            int i1 = min(j1, e - 1);
            int i2 = min(j2, e - 1);
            int i3 = min(j3, e - 1);
            int2 c0 = scv[i0];
            int2 c1 = scv[i1];
            int2 c2 = scv[i2];
            int2 c3 = scv[i3];
            float v0 = (j0 < e) ? __int_as_float(c0.y) : 0.f;
            float v1 = (j1 < e) ? __int_as_float(c1.y) : 0.f;
            float v2 = (j2 < e) ? __int_as_float(c2.y) : 0.f;
            float v3 = (j3 < e) ? __int_as_float(c3.y) : 0.f;
            float4 a0 = src[c0.x * 16 + q];
            float4 a1 = src[c1.x * 16 + q];
            float4 a2 = src[c2.x * 16 + q];
            float4 a3 = src[c3.x * 16 + q];
            acc.x += v0 * a0.x; acc.y += v0 * a0.y; acc.z += v0 * a0.z; acc.w += v0 * a0.w;
            acc.x += v1 * a1.x; acc.y += v1 * a1.y; acc.z += v1 * a1.z; acc.w += v1 * a1.w;
            acc.x += v2 * a2.x; acc.y += v2 * a2.y; acc.z += v2 * a2.z; acc.w += v2 * a2.w;
            acc.x += v3 * a3.x; acc.y += v3 * a3.y; acc.z += v3 * a3.z; acc.w += v3 * a3.w;
        }
        // reduce the 4 edge-groups (lane bits 4 and 5)
        float4 t = shfl_xor4(acc, 16);
        acc.x += t.x; acc.y += t.y; acc.z += t.z; acc.w += t.w;
        t = shfl_xor4(acc, 32);
        acc.x += t.x; acc.y += t.y; acc.z += t.z; acc.w += t.w;
        if (g == 0) {  // lanes 0..15 write the row (256B coalesced)
            float4 ev = E[(size_t)wid * 16 + q];
            acc.x += 0.1f * ev.x; acc.y += 0.1f * ev.y;
            acc.z += 0.1f * ev.z; acc.w += 0.1f * ev.w;
            dst[(size_t)wid * 16 + q] = acc;
        }
    }
}

// ---------------- launch ----------------

extern "C" void kernel_launch(void* const* d_in, const int* in_sizes, int n_in,
                              void* d_out, int out_size, void* d_ws, size_t ws_size,
                              hipStream_t stream) {
    const float* E    = (const float*)d_in[0];
    const float* eval = (const float*)d_in[1];
    const int*   erow = (const int*)d_in[2];
    const int*   ecol = (const int*)d_in[3];
    const int D   = 64;
    const int N   = in_sizes[0] / D;
    const int NNZ = in_sizes[1];
    float* out = (float*)d_out;

    char* w = (char*)d_ws;
    size_t o = 0;
    auto alloc = [&](size_t bytes) -> char* {
        char* p = w + o;
        o = (o + bytes + 255) & ~(size_t)255;
        return p;
    };
    int*   cnt  = (int*)alloc((size_t)N * 4);
    int*   rp   = (int*)alloc((size_t)(N + 1) * 4);
    int*   fill = (int*)alloc((size_t)N * 4);
    int nchunk  = (N + SCAN_T - 1) / SCAN_T;
    int*   bsum = (int*)alloc((size_t)nchunk * 4);
    int2*  scv  = (int2*)alloc((size_t)NNZ * 8);
    float* pbuf = (float*)alloc((size_t)N * D * 4);

    hipMemsetAsync(cnt, 0, (size_t)N * 4, stream);
    k_hist<<<(NNZ + 255) / 256, 256, 0, stream>>>(erow, cnt, NNZ);
    k_blocksum<<<nchunk, SCAN_T, 0, stream>>>(cnt, bsum, N);
    k_scan_bsum<<<1, SCAN_T, 0, stream>>>(bsum, nchunk);
    k_write_ptr<<<nchunk, SCAN_T, 0, stream>>>(cnt, bsum, rp, N);
    hipMemcpyAsync(fill, rp, (size_t)N * 4, hipMemcpyDeviceToDevice, stream);
    k_scatter<<<(NNZ + 255) / 256, 256, 0, stream>>>(erow, ecol, eval, fill, scv, NNZ);

    // persistent waves: 2048 blocks x 256 threads = 8192 waves, grid-stride rows
    int nblk = 2048;
    const float* src = E;
    for (int it = 0; it < 10; ++it) {
        float* dst = (it & 1) ? out : pbuf;  // it 9 (10th) -> out
        k_spmm16p<<<nblk, 256, 0, stream>>>((const float4*)src, (float4*)dst, (const float4*)E,
                                            rp, scv, N);
        src = dst;
    }
}

// Round 6
// 800.152 us; speedup vs baseline: 1.0582x; 1.0582x over previous
//
#include <hip/hip_runtime.h>

#define SCAN_T 1024

// ---------------- CSR build ----------------

__global__ void k_hist4(const int* __restrict__ row, int* __restrict__ cnt, int nnz) {
    int t = blockIdx.x * blockDim.x + threadIdx.x;
    int base = t * 4;
    if (base + 3 < nnz) {
        int4 r = *(const int4*)(row + base);
        atomicAdd(&cnt[r.x], 1);
        atomicAdd(&cnt[r.y], 1);
        atomicAdd(&cnt[r.z], 1);
        atomicAdd(&cnt[r.w], 1);
    } else {
        for (int i = base; i < nnz; ++i) atomicAdd(&cnt[row[i]], 1);
    }
}

__global__ void k_blocksum(const int* __restrict__ cnt, int* __restrict__ bsum, int n) {
    __shared__ int sm[SCAN_T];
    int tid = threadIdx.x;
    int i = blockIdx.x * SCAN_T + tid;
    int x = (i < n) ? cnt[i] : 0;
    sm[tid] = x;
    __syncthreads();
    for (int off = SCAN_T / 2; off > 0; off >>= 1) {
        if (tid < off) sm[tid] += sm[tid + off];
        __syncthreads();
    }
    if (tid == 0) bsum[blockIdx.x] = sm[0];
}

// single block: in-place exclusive scan of bsum[nchunk]
__global__ void k_scan_bsum(int* __restrict__ bsum, int nchunk) {
    __shared__ int sm[SCAN_T];
    int tid = threadIdx.x;
    int running = 0;
    for (int base = 0; base < nchunk; base += SCAN_T) {
        int i = base + tid;
        int x = (i < nchunk) ? bsum[i] : 0;
        sm[tid] = x;
        __syncthreads();
        for (int off = 1; off < SCAN_T; off <<= 1) {
            int v = (tid >= off) ? sm[tid - off] : 0;
            __syncthreads();
            sm[tid] += v;
            __syncthreads();
        }
        int incl = sm[tid];
        int total = sm[SCAN_T - 1];
        if (i < nchunk) bsum[i] = running + incl - x;  // exclusive
        running += total;
        __syncthreads();
    }
}

__global__ void k_write_ptr(const int* __restrict__ cnt, const int* __restrict__ boff,
                            int* __restrict__ rp, int n) {
    __shared__ int sm[SCAN_T];
    int tid = threadIdx.x;
    int i = blockIdx.x * SCAN_T + tid;
    int x = (i < n) ? cnt[i] : 0;
    sm[tid] = x;
    __syncthreads();
    for (int off = 1; off < SCAN_T; off <<= 1) {
        int v = (tid >= off) ? sm[tid - off] : 0;
        __syncthreads();
        sm[tid] += v;
        __syncthreads();
    }
    int incl = sm[tid];
    int base = boff[blockIdx.x];
    if (i < n) rp[i] = base + incl - x;       // exclusive
    if (i == n - 1) rp[n] = base + incl;      // total
}

__global__ void k_scatter4(const int* __restrict__ row, const int* __restrict__ col,
                           const float* __restrict__ val, int* __restrict__ fill,
                           int2* __restrict__ scv, int nnz) {
    int t = blockIdx.x * blockDim.x + threadIdx.x;
    int base = t * 4;
    if (base + 3 < nnz) {
        int4   r = *(const int4*)(row + base);
        int4   c = *(const int4*)(col + base);
        float4 v = *(const float4*)(val + base);
        int p0 = atomicAdd(&fill[r.x], 1);
        int p1 = atomicAdd(&fill[r.y], 1);
        int p2 = atomicAdd(&fill[r.z], 1);
        int p3 = atomicAdd(&fill[r.w], 1);
        scv[p0] = make_int2(c.x, __float_as_int(0.9f * v.x));
        scv[p1] = make_int2(c.y, __float_as_int(0.9f * v.y));
        scv[p2] = make_int2(c.z, __float_as_int(0.9f * v.z));
        scv[p3] = make_int2(c.w, __float_as_int(0.9f * v.w));
    } else {
        for (int i = base; i < nnz; ++i) {
            int p = atomicAdd(&fill[row[i]], 1);
            scv[p] = make_int2(col[i], __float_as_int(0.9f * val[i]));
        }
    }
}

// ---- SpMM: one wave per row. Wave-wide edge-chunk load (lane l holds edge s+l),
// then 16-edge trips: (col,val) broadcast via shuffles, 4 gathers/trip issued with
// no interleaved scv dependency. Tail lanes clamp to e-1 (dup same-address loads
// coalesce) with value predicated to 0.

__device__ __forceinline__ float4 shfl_xor4(float4 v, int m) {
    float4 r;
    r.x = __shfl_xor(v.x, m, 64);
    r.y = __shfl_xor(v.y, m, 64);
    r.z = __shfl_xor(v.z, m, 64);
    r.w = __shfl_xor(v.w, m, 64);
    return r;
}

__global__ __launch_bounds__(256) void k_spmm_wv(const float4* __restrict__ src,
                                                 float4* __restrict__ dst,
                                                 const float4* __restrict__ E,
                                                 const int* __restrict__ rp,
                                                 const int2* __restrict__ scv, int n) {
    int wid  = (blockIdx.x * blockDim.x + threadIdx.x) >> 6;  // row
    int lane = threadIdx.x & 63;
    if (wid >= n) return;
    int g = lane >> 4;   // edge group 0..3
    int q = lane & 15;   // feature quarter (4 floats each)
    int s = rp[wid];
    int e = rp[wid + 1];
    float4 acc = make_float4(0.f, 0.f, 0.f, 0.f);
    for (int base = s; base < e; base += 64) {
        int idx = base + lane;
        int2 edge = scv[min(idx, e - 1)];           // one wave-wide load per 64 edges
        float ev = (idx < e) ? __int_as_float(edge.y) : 0.f;
        int cnt = min(64, e - base);
        for (int k = 0; k < cnt; k += 16) {
            int   c0 = __shfl(edge.x, k + g, 64);
            int   c1 = __shfl(edge.x, k + 4 + g, 64);
            int   c2 = __shfl(edge.x, k + 8 + g, 64);
            int   c3 = __shfl(edge.x, k + 12 + g, 64);
            float v0 = __shfl(ev, k + g, 64);
            float v1 = __shfl(ev, k + 4 + g, 64);
            float v2 = __shfl(ev, k + 8 + g, 64);
            float v3 = __shfl(ev, k + 12 + g, 64);
            float4 a0 = src[c0 * 16 + q];
            float4 a1 = src[c1 * 16 + q];
            float4 a2 = src[c2 * 16 + q];
            float4 a3 = src[c3 * 16 + q];
            acc.x += v0 * a0.x; acc.y += v0 * a0.y; acc.z += v0 * a0.z; acc.w += v0 * a0.w;
            acc.x += v1 * a1.x; acc.y += v1 * a1.y; acc.z += v1 * a1.z; acc.w += v1 * a1.w;
            acc.x += v2 * a2.x; acc.y += v2 * a2.y; acc.z += v2 * a2.z; acc.w += v2 * a2.w;
            acc.x += v3 * a3.x; acc.y += v3 * a3.y; acc.z += v3 * a3.z; acc.w += v3 * a3.w;
        }
    }
    // reduce the 4 edge-groups (lane bits 4 and 5)
    float4 t = shfl_xor4(acc, 16);
    acc.x += t.x; acc.y += t.y; acc.z += t.z; acc.w += t.w;
    t = shfl_xor4(acc, 32);
    acc.x += t.x; acc.y += t.y; acc.z += t.z; acc.w += t.w;
    if (g == 0) {  // lanes 0..15 write the row (256B coalesced)
        float4 evec = E[(size_t)wid * 16 + q];
        acc.x += 0.1f * evec.x; acc.y += 0.1f * evec.y;
        acc.z += 0.1f * evec.z; acc.w += 0.1f * evec.w;
        dst[(size_t)wid * 16 + q] = acc;
    }
}

// ---------------- launch ----------------

extern "C" void kernel_launch(void* const* d_in, const int* in_sizes, int n_in,
                              void* d_out, int out_size, void* d_ws, size_t ws_size,
                              hipStream_t stream) {
    const float* E    = (const float*)d_in[0];
    const float* eval = (const float*)d_in[1];
    const int*   erow = (const int*)d_in[2];
    const int*   ecol = (const int*)d_in[3];
    const int D   = 64;
    const int N   = in_sizes[0] / D;
    const int NNZ = in_sizes[1];
    float* out = (float*)d_out;

    char* w = (char*)d_ws;
    size_t o = 0;
    auto alloc = [&](size_t bytes) -> char* {
        char* p = w + o;
        o = (o + bytes + 255) & ~(size_t)255;
        return p;
    };
    int*   cnt  = (int*)alloc((size_t)N * 4);
    int*   rp   = (int*)alloc((size_t)(N + 1) * 4);
    int*   fill = (int*)alloc((size_t)N * 4);
    int nchunk  = (N + SCAN_T - 1) / SCAN_T;
    int*   bsum = (int*)alloc((size_t)nchunk * 4);
    int2*  scv  = (int2*)alloc((size_t)NNZ * 8);
    float* pbuf = (float*)alloc((size_t)N * D * 4);

    hipMemsetAsync(cnt, 0, (size_t)N * 4, stream);
    int nq = (NNZ + 3) / 4;
    k_hist4<<<(nq + 255) / 256, 256, 0, stream>>>(erow, cnt, NNZ);
    k_blocksum<<<nchunk, SCAN_T, 0, stream>>>(cnt, bsum, N);
    k_scan_bsum<<<1, SCAN_T, 0, stream>>>(bsum, nchunk);
    k_write_ptr<<<nchunk, SCAN_T, 0, stream>>>(cnt, bsum, rp, N);
    hipMemcpyAsync(fill, rp, (size_t)N * 4, hipMemcpyDeviceToDevice, stream);
    k_scatter4<<<(nq + 255) / 256, 256, 0, stream>>>(erow, ecol, eval, fill, scv, NNZ);

    const int waves_per_block = 4;  // 256 threads
    int nblk = (N + waves_per_block - 1) / waves_per_block;
    const float* src = E;
    for (int it = 0; it < 10; ++it) {
        float* dst = (it & 1) ? out : pbuf;  // it 9 (10th) -> out
        k_spmm_wv<<<nblk, 256, 0, stream>>>((const float4*)src, (float4*)dst, (const float4*)E,
                                            rp, scv, N);
        src = dst;
    }
}

// Round 7
// 787.315 us; speedup vs baseline: 1.0755x; 1.0163x over previous
//
#include <hip/hip_runtime.h>

#define SCAN_T 1024

// ---------------- CSR build ----------------

__global__ void k_hist(const int* __restrict__ row, int* __restrict__ cnt, int nnz) {
    int i = blockIdx.x * blockDim.x + threadIdx.x;
    if (i < nnz) atomicAdd(&cnt[row[i]], 1);
}

__global__ void k_blocksum(const int* __restrict__ cnt, int* __restrict__ bsum, int n) {
    __shared__ int sm[SCAN_T];
    int tid = threadIdx.x;
    int i = blockIdx.x * SCAN_T + tid;
    int x = (i < n) ? cnt[i] : 0;
    sm[tid] = x;
    __syncthreads();
    for (int off = SCAN_T / 2; off > 0; off >>= 1) {
        if (tid < off) sm[tid] += sm[tid + off];
        __syncthreads();
    }
    if (tid == 0) bsum[blockIdx.x] = sm[0];
}

// single block: in-place exclusive scan of bsum[nchunk]
__global__ void k_scan_bsum(int* __restrict__ bsum, int nchunk) {
    __shared__ int sm[SCAN_T];
    int tid = threadIdx.x;
    int running = 0;
    for (int base = 0; base < nchunk; base += SCAN_T) {
        int i = base + tid;
        int x = (i < nchunk) ? bsum[i] : 0;
        sm[tid] = x;
        __syncthreads();
        for (int off = 1; off < SCAN_T; off <<= 1) {
            int v = (tid >= off) ? sm[tid - off] : 0;
            __syncthreads();
            sm[tid] += v;
            __syncthreads();
        }
        int incl = sm[tid];
        int total = sm[SCAN_T - 1];
        if (i < nchunk) bsum[i] = running + incl - x;  // exclusive
        running += total;
        __syncthreads();
    }
}

__global__ void k_write_ptr(const int* __restrict__ cnt, const int* __restrict__ boff,
                            int* __restrict__ rp, int n) {
    __shared__ int sm[SCAN_T];
    int tid = threadIdx.x;
    int i = blockIdx.x * SCAN_T + tid;
    int x = (i < n) ? cnt[i] : 0;
    sm[tid] = x;
    __syncthreads();
    for (int off = 1; off < SCAN_T; off <<= 1) {
        int v = (tid >= off) ? sm[tid - off] : 0;
        __syncthreads();
        sm[tid] += v;
        __syncthreads();
    }
    int incl = sm[tid];
    int base = boff[blockIdx.x];
    if (i < n) rp[i] = base + incl - x;       // exclusive
    if (i == n - 1) rp[n] = base + incl;      // total
}

__global__ void k_scatter(const int* __restrict__ row, const int* __restrict__ col,
                          const float* __restrict__ val, int* __restrict__ fill,
                          int2* __restrict__ scv, int nnz) {
    int i = blockIdx.x * blockDim.x + threadIdx.x;
    if (i >= nnz) return;
    int r = row[i];
    int p = atomicAdd(&fill[r], 1);
    int2 v;
    v.x = col[i];
    v.y = __float_as_int(0.9f * val[i]);   // fold (1-alpha) here
    scv[p] = v;
}

// ---- SpMM: one wave per row. Wave-wide edge-chunk load (lane l holds edge s+l),
// then 16-edge trips: (col,val) broadcast via shuffles, 4 gathers/trip. Tail lanes
// clamp to e-1 (dup same-address loads coalesce in TA) with value predicated to 0.

__device__ __forceinline__ float4 shfl_xor4(float4 v, int m) {
    float4 r;
    r.x = __shfl_xor(v.x, m, 64);
    r.y = __shfl_xor(v.y, m, 64);
    r.z = __shfl_xor(v.z, m, 64);
    r.w = __shfl_xor(v.w, m, 64);
    return r;
}

__global__ __launch_bounds__(256) void k_spmm_wv(const float4* __restrict__ src,
                                                 float4* __restrict__ dst,
                                                 const float4* __restrict__ E,
                                                 const int* __restrict__ rp,
                                                 const int2* __restrict__ scv, int n) {
    int wid  = (blockIdx.x * blockDim.x + threadIdx.x) >> 6;  // row
    int lane = threadIdx.x & 63;
    if (wid >= n) return;
    int g = lane >> 4;   // edge group 0..3
    int q = lane & 15;   // feature quarter (4 floats each)
    int s = rp[wid];
    int e = rp[wid + 1];
    float4 acc = make_float4(0.f, 0.f, 0.f, 0.f);
    for (int base = s; base < e; base += 64) {
        int idx = base + lane;
        int2 edge = scv[min(idx, e - 1)];           // one wave-wide load per 64 edges
        float ev = (idx < e) ? __int_as_float(edge.y) : 0.f;
        int cnt = min(64, e - base);
        for (int k = 0; k < cnt; k += 16) {
            int   c0 = __shfl(edge.x, k + g, 64);
            int   c1 = __shfl(edge.x, k + 4 + g, 64);
            int   c2 = __shfl(edge.x, k + 8 + g, 64);
            int   c3 = __shfl(edge.x, k + 12 + g, 64);
            float v0 = __shfl(ev, k + g, 64);
            float v1 = __shfl(ev, k + 4 + g, 64);
            float v2 = __shfl(ev, k + 8 + g, 64);
            float v3 = __shfl(ev, k + 12 + g, 64);
            float4 a0 = src[c0 * 16 + q];
            float4 a1 = src[c1 * 16 + q];
            float4 a2 = src[c2 * 16 + q];
            float4 a3 = src[c3 * 16 + q];
            acc.x += v0 * a0.x; acc.y += v0 * a0.y; acc.z += v0 * a0.z; acc.w += v0 * a0.w;
            acc.x += v1 * a1.x; acc.y += v1 * a1.y; acc.z += v1 * a1.z; acc.w += v1 * a1.w;
            acc.x += v2 * a2.x; acc.y += v2 * a2.y; acc.z += v2 * a2.z; acc.w += v2 * a2.w;
            acc.x += v3 * a3.x; acc.y += v3 * a3.y; acc.z += v3 * a3.z; acc.w += v3 * a3.w;
        }
    }
    // reduce the 4 edge-groups (lane bits 4 and 5)
    float4 t = shfl_xor4(acc, 16);
    acc.x += t.x; acc.y += t.y; acc.z += t.z; acc.w += t.w;
    t = shfl_xor4(acc, 32);
    acc.x += t.x; acc.y += t.y; acc.z += t.z; acc.w += t.w;
    if (g == 0) {  // lanes 0..15 write the row (256B coalesced)
        float4 evec = E[(size_t)wid * 16 + q];
        acc.x += 0.1f * evec.x; acc.y += 0.1f * evec.y;
        acc.z += 0.1f * evec.z; acc.w += 0.1f * evec.w;
        dst[(size_t)wid * 16 + q] = acc;
    }
}

// ---------------- launch ----------------

extern "C" void kernel_launch(void* const* d_in, const int* in_sizes, int n_in,
                              void* d_out, int out_size, void* d_ws, size_t ws_size,
                              hipStream_t stream) {
    const float* E    = (const float*)d_in[0];
    const float* eval = (const float*)d_in[1];
    const int*   erow = (const int*)d_in[2];
    const int*   ecol = (const int*)d_in[3];
    const int D   = 64;
    const int N   = in_sizes[0] / D;
    const int NNZ = in_sizes[1];
    float* out = (float*)d_out;

    char* w = (char*)d_ws;
    size_t o = 0;
    auto alloc = [&](size_t bytes) -> char* {
        char* p = w + o;
        o = (o + bytes + 255) & ~(size_t)255;
        return p;
    };
    int*   cnt  = (int*)alloc((size_t)N * 4);
    int*   rp   = (int*)alloc((size_t)(N + 1) * 4);
    int*   fill = (int*)alloc((size_t)N * 4);
    int nchunk  = (N + SCAN_T - 1) / SCAN_T;
    int*   bsum = (int*)alloc((size_t)nchunk * 4);
    int2*  scv  = (int2*)alloc((size_t)NNZ * 8);
    float* pbuf = (float*)alloc((size_t)N * D * 4);

    hipMemsetAsync(cnt, 0, (size_t)N * 4, stream);
    k_hist<<<(NNZ + 255) / 256, 256, 0, stream>>>(erow, cnt, NNZ);
    k_blocksum<<<nchunk, SCAN_T, 0, stream>>>(cnt, bsum, N);
    k_scan_bsum<<<1, SCAN_T, 0, stream>>>(bsum, nchunk);
    k_write_ptr<<<nchunk, SCAN_T, 0, stream>>>(cnt, bsum, rp, N);
    hipMemcpyAsync(fill, rp, (size_t)N * 4, hipMemcpyDeviceToDevice, stream);
    k_scatter<<<(NNZ + 255) / 256, 256, 0, stream>>>(erow, ecol, eval, fill, scv, NNZ);

    const int waves_per_block = 4;  // 256 threads
    int nblk = (N + waves_per_block - 1) / waves_per_block;
    const float* src = E;
    for (int it = 0; it < 10; ++it) {
        float* dst = (it & 1) ? out : pbuf;  // it 9 (10th) -> out
        k_spmm_wv<<<nblk, 256, 0, stream>>>((const float4*)src, (float4*)dst, (const float4*)E,
                                            rp, scv, N);
        src = dst;
    }
}

// Round 8
// 647.918 us; speedup vs baseline: 1.3068x; 1.2151x over previous
//
#include <hip/hip_runtime.h>

#define NBSH 7                 // 128 rows per bucket
#define ROWS_PB 128
#define NB_MAX 1024            // requires N <= 131072

// ---------------- bucketed CSR build ----------------

// A: bucket histogram, LDS-aggregated per block
__global__ __launch_bounds__(1024) void k_bhist(const int* __restrict__ row,
                                                int* __restrict__ bcnt, int nnz, int nb) {
    __shared__ int h[NB_MAX];
    for (int i = threadIdx.x; i < nb; i += 1024) h[i] = 0;
    __syncthreads();
    int stride = gridDim.x * 1024;
    for (int i = blockIdx.x * 1024 + threadIdx.x; i < nnz; i += stride)
        atomicAdd(&h[row[i] >> NBSH], 1);
    __syncthreads();
    for (int i = threadIdx.x; i < nb; i += 1024) {
        int c = h[i];
        if (c) atomicAdd(&bcnt[i], c);
    }
}

// B: single-block exclusive scan of bucket counts -> bptr, bfill; also rp[n]=nnz
__global__ __launch_bounds__(1024) void k_bscan(const int* __restrict__ bcnt,
                                                int* __restrict__ bptr, int* __restrict__ bfill,
                                                int* __restrict__ rp, int nb, int n, int nnz) {
    __shared__ int sm[NB_MAX];
    int tid = threadIdx.x;
    int x = (tid < nb) ? bcnt[tid] : 0;
    sm[tid] = x;
    __syncthreads();
    for (int off = 1; off < NB_MAX; off <<= 1) {
        int v = (tid >= off) ? sm[tid - off] : 0;
        __syncthreads();
        sm[tid] += v;
        __syncthreads();
    }
    if (tid < nb) {
        int ex = sm[tid] - x;
        bptr[tid] = ex;
        bfill[tid] = ex;
    }
    if (tid == 0) { bptr[nb] = nnz; rp[n] = nnz; }
}

// C: bin edges into bucket-ordered ebuf. Block reserves per-bucket space with ONE
// global atomic per touched bucket; writes cluster at ~nb moving fronts (L2-resident
// -> full-sector HBM writes). Record: x = col | (rowlocal<<20), y = 0.9*val bits.
__global__ __launch_bounds__(1024) void k_bin(const int* __restrict__ row,
                                              const int* __restrict__ col,
                                              const float* __restrict__ val,
                                              int* __restrict__ bfill, int2* __restrict__ ebuf,
                                              int nnz, int nb, int ch) {
    __shared__ int h[NB_MAX];
    __shared__ int cur[NB_MAX];
    int tid = threadIdx.x;
    int start = blockIdx.x * ch;
    int end = min(start + ch, nnz);
    for (int i = tid; i < nb; i += 1024) { h[i] = 0; cur[i] = 0; }
    __syncthreads();
    for (int i = start + tid; i < end; i += 1024)
        atomicAdd(&h[row[i] >> NBSH], 1);
    __syncthreads();
    for (int i = tid; i < nb; i += 1024) {
        int c = h[i];
        h[i] = c ? atomicAdd(&bfill[i], c) : 0;
    }
    __syncthreads();
    for (int i = start + tid; i < end; i += 1024) {
        int r = row[i];
        int b = r >> NBSH;
        int sl = atomicAdd(&cur[b], 1);
        int2 e;
        e.x = col[i] | ((r & (ROWS_PB - 1)) << 20);
        e.y = __float_as_int(0.9f * val[i]);
        ebuf[h[b] + sl] = e;
    }
}

// D: per-bucket local CSR: 128-row LDS hist + scan -> rp, then scatter into the
// bucket's contiguous scv window (L2-absorbed, full-line evictions).
__global__ __launch_bounds__(ROWS_PB) void k_csr(const int2* __restrict__ ebuf,
                                                 const int* __restrict__ bptr,
                                                 int* __restrict__ rp, int2* __restrict__ scv,
                                                 int n, int nb) {
    __shared__ int hist[ROWS_PB];
    __shared__ int cur[ROWS_PB];
    int b = blockIdx.x;
    int tid = threadIdx.x;
    int s = bptr[b], e = bptr[b + 1];
    hist[tid] = 0;
    __syncthreads();
    for (int i = s + tid; i < e; i += ROWS_PB)
        atomicAdd(&hist[(ebuf[i].x >> 20) & (ROWS_PB - 1)], 1);
    __syncthreads();
    int x = hist[tid];
    __syncthreads();
    for (int off = 1; off < ROWS_PB; off <<= 1) {
        int v = (tid >= off) ? hist[tid - off] : 0;
        __syncthreads();
        hist[tid] += v;
        __syncthreads();
    }
    int excl = hist[tid] - x;
    int base = s + excl;
    int grow = b * ROWS_PB + tid;
    if (grow < n) rp[grow] = base;
    cur[tid] = base;
    __syncthreads();
    for (int i = s + tid; i < e; i += ROWS_PB) {
        int2 ebi = ebuf[i];
        int rl = (ebi.x >> 20) & (ROWS_PB - 1);
        int p = atomicAdd(&cur[rl], 1);
        scv[p] = make_int2(ebi.x & 0xFFFFF, ebi.y);
    }
}

// ---- SpMM: one wave per row. Wave-wide edge-chunk load (lane l holds edge s+l),
// then 16-edge trips: (col,val) broadcast via shuffles, 4 gathers/trip. Tail lanes
// clamp to e-1 (dup same-address loads coalesce in TA) with value predicated to 0.

__device__ __forceinline__ float4 shfl_xor4(float4 v, int m) {
    float4 r;
    r.x = __shfl_xor(v.x, m, 64);
    r.y = __shfl_xor(v.y, m, 64);
    r.z = __shfl_xor(v.z, m, 64);
    r.w = __shfl_xor(v.w, m, 64);
    return r;
}

__global__ __launch_bounds__(256) void k_spmm_wv(const float4* __restrict__ src,
                                                 float4* __restrict__ dst,
                                                 const float4* __restrict__ E,
                                                 const int* __restrict__ rp,
                                                 const int2* __restrict__ scv, int n) {
    int wid  = (blockIdx.x * blockDim.x + threadIdx.x) >> 6;  // row
    int lane = threadIdx.x & 63;
    if (wid >= n) return;
    int g = lane >> 4;   // edge group 0..3
    int q = lane & 15;   // feature quarter (4 floats each)
    int s = rp[wid];
    int e = rp[wid + 1];
    float4 acc = make_float4(0.f, 0.f, 0.f, 0.f);
    for (int base = s; base < e; base += 64) {
        int idx = base + lane;
        int2 edge = scv[min(idx, e - 1)];           // one wave-wide load per 64 edges
        float ev = (idx < e) ? __int_as_float(edge.y) : 0.f;
        int cnt = min(64, e - base);
        for (int k = 0; k < cnt; k += 16) {
            int   c0 = __shfl(edge.x, k + g, 64);
            int   c1 = __shfl(edge.x, k + 4 + g, 64);
            int   c2 = __shfl(edge.x, k + 8 + g, 64);
            int   c3 = __shfl(edge.x, k + 12 + g, 64);
            float v0 = __shfl(ev, k + g, 64);
            float v1 = __shfl(ev, k + 4 + g, 64);
            float v2 = __shfl(ev, k + 8 + g, 64);
            float v3 = __shfl(ev, k + 12 + g, 64);
            float4 a0 = src[c0 * 16 + q];
            float4 a1 = src[c1 * 16 + q];
            float4 a2 = src[c2 * 16 + q];
            float4 a3 = src[c3 * 16 + q];
            acc.x += v0 * a0.x; acc.y += v0 * a0.y; acc.z += v0 * a0.z; acc.w += v0 * a0.w;
            acc.x += v1 * a1.x; acc.y += v1 * a1.y; acc.z += v1 * a1.z; acc.w += v1 * a1.w;
            acc.x += v2 * a2.x; acc.y += v2 * a2.y; acc.z += v2 * a2.z; acc.w += v2 * a2.w;
            acc.x += v3 * a3.x; acc.y += v3 * a3.y; acc.z += v3 * a3.z; acc.w += v3 * a3.w;
        }
    }
    // reduce the 4 edge-groups (lane bits 4 and 5)
    float4 t = shfl_xor4(acc, 16);
    acc.x += t.x; acc.y += t.y; acc.z += t.z; acc.w += t.w;
    t = shfl_xor4(acc, 32);
    acc.x += t.x; acc.y += t.y; acc.z += t.z; acc.w += t.w;
    if (g == 0) {  // lanes 0..15 write the row (256B coalesced)
        float4 evec = E[(size_t)wid * 16 + q];
        acc.x += 0.1f * evec.x; acc.y += 0.1f * evec.y;
        acc.z += 0.1f * evec.z; acc.w += 0.1f * evec.w;
        dst[(size_t)wid * 16 + q] = acc;
    }
}

// ---------------- launch ----------------

extern "C" void kernel_launch(void* const* d_in, const int* in_sizes, int n_in,
                              void* d_out, int out_size, void* d_ws, size_t ws_size,
                              hipStream_t stream) {
    const float* E    = (const float*)d_in[0];
    const float* eval = (const float*)d_in[1];
    const int*   erow = (const int*)d_in[2];
    const int*   ecol = (const int*)d_in[3];
    const int D   = 64;
    const int N   = in_sizes[0] / D;
    const int NNZ = in_sizes[1];
    float* out = (float*)d_out;

    int NB = (N + ROWS_PB - 1) >> NBSH;   // <= 1024 for N <= 131072

    char* w = (char*)d_ws;
    size_t o = 0;
    auto alloc = [&](size_t bytes) -> char* {
        char* p = w + o;
        o = (o + bytes + 255) & ~(size_t)255;
        return p;
    };
    int*  bcnt  = (int*)alloc((size_t)NB * 4);
    int*  bptr  = (int*)alloc((size_t)(NB + 1) * 4);
    int*  bfill = (int*)alloc((size_t)NB * 4);
    int*  rp    = (int*)alloc((size_t)(N + 1) * 4);
    int2* scv   = (int2*)alloc((size_t)NNZ * 8);
    // ebuf dead after k_csr -> pbuf overlaps it
    char* unionbase = alloc((size_t)NNZ * 8 > (size_t)N * D * 4 ? (size_t)NNZ * 8
                                                                : (size_t)N * D * 4);
    int2*  ebuf = (int2*)unionbase;
    float* pbuf = (float*)unionbase;

    hipMemsetAsync(bcnt, 0, (size_t)NB * 4, stream);
    k_bhist<<<256, 1024, 0, stream>>>(erow, bcnt, NNZ, NB);
    k_bscan<<<1, NB_MAX, 0, stream>>>(bcnt, bptr, bfill, rp, NB, N, NNZ);
    int ch = (NNZ + 255) / 256;
    k_bin<<<256, 1024, 0, stream>>>(erow, ecol, eval, bfill, ebuf, NNZ, NB, ch);
    k_csr<<<NB, ROWS_PB, 0, stream>>>(ebuf, bptr, rp, scv, N, NB);

    const int waves_per_block = 4;  // 256 threads
    int nblk = (N + waves_per_block - 1) / waves_per_block;
    const float* src = E;
    for (int it = 0; it < 10; ++it) {
        float* dst = (it & 1) ? out : pbuf;  // it 9 (10th) -> out
        k_spmm_wv<<<nblk, 256, 0, stream>>>((const float4*)src, (float4*)dst, (const float4*)E,
                                            rp, scv, N);
        src = dst;
    }
}

// Round 9
// 638.810 us; speedup vs baseline: 1.3255x; 1.0143x over previous
//
#include <hip/hip_runtime.h>

#define NBSH 7                 // 128 rows per bucket
#define ROWS_PB 128
#define NB_MAX 1024            // requires N <= 131072

// ---------------- bucketed CSR build ----------------

// A: bucket histogram, LDS-aggregated per block
__global__ __launch_bounds__(1024) void k_bhist(const int* __restrict__ row,
                                                int* __restrict__ bcnt, int nnz, int nb) {
    __shared__ int h[NB_MAX];
    for (int i = threadIdx.x; i < nb; i += 1024) h[i] = 0;
    __syncthreads();
    int stride = gridDim.x * 1024;
    for (int i = blockIdx.x * 1024 + threadIdx.x; i < nnz; i += stride)
        atomicAdd(&h[row[i] >> NBSH], 1);
    __syncthreads();
    for (int i = threadIdx.x; i < nb; i += 1024) {
        int c = h[i];
        if (c) atomicAdd(&bcnt[i], c);
    }
}

// B: single-block exclusive scan of bucket counts -> bptr, bfill; also rp[n]=nnz
__global__ __launch_bounds__(1024) void k_bscan(const int* __restrict__ bcnt,
                                                int* __restrict__ bptr, int* __restrict__ bfill,
                                                int* __restrict__ rp, int nb, int n, int nnz) {
    __shared__ int sm[NB_MAX];
    int tid = threadIdx.x;
    int x = (tid < nb) ? bcnt[tid] : 0;
    sm[tid] = x;
    __syncthreads();
    for (int off = 1; off < NB_MAX; off <<= 1) {
        int v = (tid >= off) ? sm[tid - off] : 0;
        __syncthreads();
        sm[tid] += v;
        __syncthreads();
    }
    if (tid < nb) {
        int ex = sm[tid] - x;
        bptr[tid] = ex;
        bfill[tid] = ex;
    }
    if (tid == 0) { bptr[nb] = nnz; rp[n] = nnz; }
}

// C: bin edges into bucket-ordered ebuf. Block reserves per-bucket space with ONE
// global atomic per touched bucket; writes cluster at ~nb moving fronts (L2-resident
// -> full-sector HBM writes). Record: x = col | (rowlocal<<20), y = 0.9*val bits.
__global__ __launch_bounds__(1024) void k_bin(const int* __restrict__ row,
                                              const int* __restrict__ col,
                                              const float* __restrict__ val,
                                              int* __restrict__ bfill, int2* __restrict__ ebuf,
                                              int nnz, int nb, int ch) {
    __shared__ int h[NB_MAX];
    __shared__ int cur[NB_MAX];
    int tid = threadIdx.x;
    int start = blockIdx.x * ch;
    int end = min(start + ch, nnz);
    for (int i = tid; i < nb; i += 1024) { h[i] = 0; cur[i] = 0; }
    __syncthreads();
    for (int i = start + tid; i < end; i += 1024)
        atomicAdd(&h[row[i] >> NBSH], 1);
    __syncthreads();
    for (int i = tid; i < nb; i += 1024) {
        int c = h[i];
        h[i] = c ? atomicAdd(&bfill[i], c) : 0;
    }
    __syncthreads();
    for (int i = start + tid; i < end; i += 1024) {
        int r = row[i];
        int b = r >> NBSH;
        int sl = atomicAdd(&cur[b], 1);
        int2 e;
        e.x = col[i] | ((r & (ROWS_PB - 1)) << 20);
        e.y = __float_as_int(0.9f * val[i]);
        ebuf[h[b] + sl] = e;
    }
}

// D: per-bucket local CSR: 128-row LDS hist + scan -> rp, then scatter into the
// bucket's contiguous scv window (L2-absorbed, full-line evictions).
__global__ __launch_bounds__(ROWS_PB) void k_csr(const int2* __restrict__ ebuf,
                                                 const int* __restrict__ bptr,
                                                 int* __restrict__ rp, int2* __restrict__ scv,
                                                 int n, int nb) {
    __shared__ int hist[ROWS_PB];
    __shared__ int cur[ROWS_PB];
    int b = blockIdx.x;
    int tid = threadIdx.x;
    int s = bptr[b], e = bptr[b + 1];
    hist[tid] = 0;
    __syncthreads();
    for (int i = s + tid; i < e; i += ROWS_PB)
        atomicAdd(&hist[(ebuf[i].x >> 20) & (ROWS_PB - 1)], 1);
    __syncthreads();
    int x = hist[tid];
    __syncthreads();
    for (int off = 1; off < ROWS_PB; off <<= 1) {
        int v = (tid >= off) ? hist[tid - off] : 0;
        __syncthreads();
        hist[tid] += v;
        __syncthreads();
    }
    int excl = hist[tid] - x;
    int base = s + excl;
    int grow = b * ROWS_PB + tid;
    if (grow < n) rp[grow] = base;
    cur[tid] = base;
    __syncthreads();
    for (int i = s + tid; i < e; i += ROWS_PB) {
        int2 ebi = ebuf[i];
        int rl = (ebi.x >> 20) & (ROWS_PB - 1);
        int p = atomicAdd(&cur[rl], 1);
        scv[p] = make_int2(ebi.x & 0xFFFFF, ebi.y);
    }
}

// ---- SpMM: TWO rows per wave, fully interleaved (2 independent scv loads,
// 8 independent gathers/trip, 2 accumulators). Wave-wide edge-chunk loads,
// (col,val) broadcast via shuffles. Tails clamp to [0, e-1] (dup same-address
// gathers coalesce in TA) with value predicated to 0.

__device__ __forceinline__ float4 shfl_xor4(float4 v, int m) {
    float4 r;
    r.x = __shfl_xor(v.x, m, 64);
    r.y = __shfl_xor(v.y, m, 64);
    r.z = __shfl_xor(v.z, m, 64);
    r.w = __shfl_xor(v.w, m, 64);
    return r;
}

__global__ __launch_bounds__(256) void k_spmm_wv2(const float4* __restrict__ src,
                                                  float4* __restrict__ dst,
                                                  const float4* __restrict__ E,
                                                  const int* __restrict__ rp,
                                                  const int2* __restrict__ scv, int n) {
    int wv   = (blockIdx.x * blockDim.x + threadIdx.x) >> 6;
    int lane = threadIdx.x & 63;
    int r0 = wv * 2;
    if (r0 >= n) return;
    int r1 = r0 + 1;
    bool v1 = (r1 < n);
    int g = lane >> 4;   // edge group 0..3
    int q = lane & 15;   // feature quarter (4 floats each)
    int s0 = rp[r0];
    int e0 = rp[r0 + 1];
    int s1 = v1 ? e0 : 0;               // CSR contiguity: rp[r1] == e0
    int e1 = v1 ? rp[r1 + 1] : 1;
    float4 acc0 = make_float4(0.f, 0.f, 0.f, 0.f);
    float4 acc1 = make_float4(0.f, 0.f, 0.f, 0.f);
    int b0 = s0, b1 = s1;
    while (b0 < e0 || b1 < e1) {
        int i0 = b0 + lane;
        int i1 = b1 + lane;
        int2 ed0 = scv[max(min(i0, e0 - 1), 0)];   // wave-wide chunk loads
        int2 ed1 = scv[max(min(i1, e1 - 1), 0)];
        float ev0 = (i0 < e0) ? __int_as_float(ed0.y) : 0.f;
        float ev1 = (v1 && i1 < e1) ? __int_as_float(ed1.y) : 0.f;
        int cnt = min(64, max(e0 - b0, e1 - b1));
        for (int k = 0; k < cnt; k += 16) {
            int   c00 = __shfl(ed0.x, k + g, 64);
            int   c01 = __shfl(ed0.x, k + 4 + g, 64);
            int   c02 = __shfl(ed0.x, k + 8 + g, 64);
            int   c03 = __shfl(ed0.x, k + 12 + g, 64);
            int   c10 = __shfl(ed1.x, k + g, 64);
            int   c11 = __shfl(ed1.x, k + 4 + g, 64);
            int   c12 = __shfl(ed1.x, k + 8 + g, 64);
            int   c13 = __shfl(ed1.x, k + 12 + g, 64);
            float w00 = __shfl(ev0, k + g, 64);
            float w01 = __shfl(ev0, k + 4 + g, 64);
            float w02 = __shfl(ev0, k + 8 + g, 64);
            float w03 = __shfl(ev0, k + 12 + g, 64);
            float w10 = __shfl(ev1, k + g, 64);
            float w11 = __shfl(ev1, k + 4 + g, 64);
            float w12 = __shfl(ev1, k + 8 + g, 64);
            float w13 = __shfl(ev1, k + 12 + g, 64);
            float4 a00 = src[c00 * 16 + q];
            float4 a01 = src[c01 * 16 + q];
            float4 a02 = src[c02 * 16 + q];
            float4 a03 = src[c03 * 16 + q];
            float4 a10 = src[c10 * 16 + q];
            float4 a11 = src[c11 * 16 + q];
            float4 a12 = src[c12 * 16 + q];
            float4 a13 = src[c13 * 16 + q];
            acc0.x += w00 * a00.x; acc0.y += w00 * a00.y; acc0.z += w00 * a00.z; acc0.w += w00 * a00.w;
            acc0.x += w01 * a01.x; acc0.y += w01 * a01.y; acc0.z += w01 * a01.z; acc0.w += w01 * a01.w;
            acc0.x += w02 * a02.x; acc0.y += w02 * a02.y; acc0.z += w02 * a02.z; acc0.w += w02 * a02.w;
            acc0.x += w03 * a03.x; acc0.y += w03 * a03.y; acc0.z += w03 * a03.z; acc0.w += w03 * a03.w;
            acc1.x += w10 * a10.x; acc1.y += w10 * a10.y; acc1.z += w10 * a10.z; acc1.w += w10 * a10.w;
            acc1.x += w11 * a11.x; acc1.y += w11 * a11.y; acc1.z += w11 * a11.z; acc1.w += w11 * a11.w;
            acc1.x += w12 * a12.x; acc1.y += w12 * a12.y; acc1.z += w12 * a12.z; acc1.w += w12 * a12.w;
            acc1.x += w13 * a13.x; acc1.y += w13 * a13.y; acc1.z += w13 * a13.z; acc1.w += w13 * a13.w;
        }
        b0 += 64;
        b1 += 64;
    }
    // reduce the 4 edge-groups (lane bits 4 and 5)
    float4 t = shfl_xor4(acc0, 16);
    acc0.x += t.x; acc0.y += t.y; acc0.z += t.z; acc0.w += t.w;
    t = shfl_xor4(acc0, 32);
    acc0.x += t.x; acc0.y += t.y; acc0.z += t.z; acc0.w += t.w;
    t = shfl_xor4(acc1, 16);
    acc1.x += t.x; acc1.y += t.y; acc1.z += t.z; acc1.w += t.w;
    t = shfl_xor4(acc1, 32);
    acc1.x += t.x; acc1.y += t.y; acc1.z += t.z; acc1.w += t.w;
    if (g == 0) {          // lanes 0..15: row r0
        float4 evec = E[(size_t)r0 * 16 + q];
        acc0.x += 0.1f * evec.x; acc0.y += 0.1f * evec.y;
        acc0.z += 0.1f * evec.z; acc0.w += 0.1f * evec.w;
        dst[(size_t)r0 * 16 + q] = acc0;
    } else if (g == 1 && v1) {  // lanes 16..31: row r1 (adjacent 256B -> merged store)
        float4 evec = E[(size_t)r1 * 16 + q];
        acc1.x += 0.1f * evec.x; acc1.y += 0.1f * evec.y;
        acc1.z += 0.1f * evec.z; acc1.w += 0.1f * evec.w;
        dst[(size_t)r1 * 16 + q] = acc1;
    }
}

// ---------------- launch ----------------

extern "C" void kernel_launch(void* const* d_in, const int* in_sizes, int n_in,
                              void* d_out, int out_size, void* d_ws, size_t ws_size,
                              hipStream_t stream) {
    const float* E    = (const float*)d_in[0];
    const float* eval = (const float*)d_in[1];
    const int*   erow = (const int*)d_in[2];
    const int*   ecol = (const int*)d_in[3];
    const int D   = 64;
    const int N   = in_sizes[0] / D;
    const int NNZ = in_sizes[1];
    float* out = (float*)d_out;

    int NB = (N + ROWS_PB - 1) >> NBSH;   // <= 1024 for N <= 131072

    char* w = (char*)d_ws;
    size_t o = 0;
    auto alloc = [&](size_t bytes) -> char* {
        char* p = w + o;
        o = (o + bytes + 255) & ~(size_t)255;
        return p;
    };
    int*  bcnt  = (int*)alloc((size_t)NB * 4);
    int*  bptr  = (int*)alloc((size_t)(NB + 1) * 4);
    int*  bfill = (int*)alloc((size_t)NB * 4);
    int*  rp    = (int*)alloc((size_t)(N + 1) * 4);
    int2* scv   = (int2*)alloc((size_t)NNZ * 8);
    // ebuf dead after k_csr -> pbuf overlaps it
    char* unionbase = alloc((size_t)NNZ * 8 > (size_t)N * D * 4 ? (size_t)NNZ * 8
                                                                : (size_t)N * D * 4);
    int2*  ebuf = (int2*)unionbase;
    float* pbuf = (float*)unionbase;

    hipMemsetAsync(bcnt, 0, (size_t)NB * 4, stream);
    k_bhist<<<256, 1024, 0, stream>>>(erow, bcnt, NNZ, NB);
    k_bscan<<<1, NB_MAX, 0, stream>>>(bcnt, bptr, bfill, rp, NB, N, NNZ);
    int ch = (NNZ + 255) / 256;
    k_bin<<<256, 1024, 0, stream>>>(erow, ecol, eval, bfill, ebuf, NNZ, NB, ch);
    k_csr<<<NB, ROWS_PB, 0, stream>>>(ebuf, bptr, rp, scv, N, NB);

    // 2 rows per wave, 4 waves per block
    int nwaves = (N + 1) / 2;
    int nblk = (nwaves + 3) / 4;
    const float* src = E;
    for (int it = 0; it < 10; ++it) {
        float* dst = (it & 1) ? out : pbuf;  // it 9 (10th) -> out
        k_spmm_wv2<<<nblk, 256, 0, stream>>>((const float4*)src, (float4*)dst,
                                             (const float4*)E, rp, scv, N);
        src = dst;
    }
}